// Round 11
// baseline (621.221 us; speedup 1.0000x reference)
//
#include <hip/hip_runtime.h>
#include <hip/hip_bf16.h>

// ClassAtt fused pipeline. R11 = R10 (B operand in registers, A-only LDS ring)
// with ALL counted vmcnt waits replaced by a conservative full drain
// (vmcnt0+lgkm0+barrier once per K-tile) — provably race-free (R7 pattern).
// Discriminator: if R10's failure was the counted-wait ledger, this passes
// and keeps the 130KB->81KB LDS-traffic reduction per K-tile.

typedef __bf16 bf16_t;
typedef __bf16 bf16x4 __attribute__((ext_vector_type(4)));
typedef __bf16 bf16x8 __attribute__((ext_vector_type(8)));
typedef float  f32x4  __attribute__((ext_vector_type(4)));

#define AS1(p) (const __attribute__((address_space(1))) void*)(p)
#define AS3(p) (__attribute__((address_space(3))) void*)(p)

// ---------------- f32 -> bf16 conversion (tube) ----------------
__global__ void cvt_f32_bf16_v4(const float* __restrict__ src, bf16_t* __restrict__ dst,
                                int n4src, int n4tot) {
  for (int i = blockIdx.x * blockDim.x + threadIdx.x; i < n4tot; i += gridDim.x * blockDim.x) {
    bf16x4 o;
    if (i < n4src) {
      float4 f = ((const float4*)src)[i];
      o[0] = (bf16_t)f.x; o[1] = (bf16_t)f.y; o[2] = (bf16_t)f.z; o[3] = (bf16_t)f.w;
    } else {
      o[0] = (bf16_t)0.0f; o[1] = (bf16_t)0.0f; o[2] = (bf16_t)0.0f; o[3] = (bf16_t)0.0f;
    }
    *(bf16x4*)(dst + (size_t)i * 4) = o;
  }
}

// ---------------- all weight cvts merged (one launch) ----------------
__global__ void cvt_weights(const float* __restrict__ w1, const float* __restrict__ w2,
                            const float* __restrict__ w3, const float* __restrict__ wh,
                            const float* __restrict__ wd1, const float* __restrict__ wd2,
                            bf16_t* __restrict__ w123, bf16_t* __restrict__ whB,
                            bf16_t* __restrict__ wd1B, bf16_t* __restrict__ wd2B) {
  const int stride = gridDim.x * blockDim.x;
  for (int i = blockIdx.x * blockDim.x + threadIdx.x; i < 2752512; i += stride) {
    const float* s; bf16_t* d; int o; int ns = 1 << 30;
    if (i < 131072)       { s = w1;  d = w123;           o = i; }
    else if (i < 262144)  { s = w2;  d = w123 + 524288;  o = i - 131072; }
    else if (i < 393216)  { s = w3;  d = w123 + 1048576; o = i - 262144; }
    else if (i < 1179648) { s = wh;  d = whB;            o = i - 393216; }
    else if (i < 2228224) { s = wd1; d = wd1B;           o = i - 1179648; }
    else                  { s = wd2; d = wd2B;           o = i - 2228224; ns = 512000; }
    bf16x4 v;
    if (o < ns) {
      float4 f = ((const float4*)s)[o];
      v[0] = (bf16_t)f.x; v[1] = (bf16_t)f.y; v[2] = (bf16_t)f.z; v[3] = (bf16_t)f.w;
    } else {
      v[0] = (bf16_t)0.0f; v[1] = (bf16_t)0.0f; v[2] = (bf16_t)0.0f; v[3] = (bf16_t)0.0f;
    }
    *(bf16x4*)(d + (size_t)o * 4) = v;
  }
}

__global__ void concat_bias3(const float* __restrict__ a, const float* __restrict__ b,
                             const float* __restrict__ c, float* __restrict__ dst) {
  int i = blockIdx.x * blockDim.x + threadIdx.x;
  if (i < 1024) dst[i] = a[i];
  else if (i < 2048) dst[i] = b[i - 1024];
  else if (i < 3072) dst[i] = c[i - 2048];
}

// ---------------- GEMM: C = act(A @ Bw^T + bias), 256x256 tile ----------------
// 512 threads = 8 waves (2M x 4N), wave tile 128x64 = acc[8][4] 16x16 frags.
// A: LDS 4-slot ring (64 KiB dynamic), R2 staging + XOR swizzle (conflict-free).
// B: global->VGPR (same element set as the verified LDS path), bE/bO
// double-buffer, prefetched 1 tile ahead.
// Sync: ONE full drain (vmcnt0+lgkm0+barrier) per K-tile — provably safe:
// stage of slot X issues >=1 barrier after slot X's readers drained; every
// staged tile drains the iteration it was issued (span ~2200cy >> HBM lat).
template<bool BDIAG, bool RELU, bool OUT_BF16>
__global__ __launch_bounds__(512, 2)
void gemm256(const bf16_t* __restrict__ A, int lda,
             const bf16_t* __restrict__ Bw, int ldb,
             const float* __restrict__ bias,
             void* __restrict__ Cout, int ldc,
             int K, int Nmask, int nbx)
{
  extern __shared__ char lds[];
  bf16_t* Ab = (bf16_t*)lds;               // 4 slots x 8192 elems (16 KiB/slot)

  const int t   = threadIdx.x;
  const int ln  = t & 63;
  const int w   = t >> 6;
  const int l15 = ln & 15, lhi = ln >> 4;
  const int wm  = w >> 2, wn = w & 3;

  // XCD-chunked block swizzle (grid divisible by 8)
  const int nb = (int)gridDim.x;
  const int id = (int)blockIdx.x;
  const int id_sw = (id & 7) * (nb >> 3) + (id >> 3);
  const int bx = id_sw % nbx, by = id_sw / nbx;
  const int rowBase = by * 256;
  const int colBase = bx * 256;
  const int aCol0 = BDIAG ? (colBase >> 10) * 512 : 0;

  // A staging (R2-verified): thread t -> LDS row i*128 + w*16 + ln/4, linear
  // 16B dest; source granule pre-swizzled with key=(row>>1)&3 involution.
  const int srow = (w << 4) + (ln >> 2);
  const int scol = (((ln & 3) ^ (ln >> 3)) & 3) << 3;
  const bf16_t* aS = A + (size_t)(rowBase + srow) * lda + aCol0 + scol;
  const size_t aI = (size_t)128 * lda;
  bf16_t* daW = Ab + (w << 9);

  // A fragment read offsets (elements), swizzle involution re-applied
  const int key  = (l15 >> 1) & 3;
  const int fcol = (lhi ^ key) << 3;
  const int aOff = (wm * 128 + l15) * 32 + fcol;   // + mf*512 + slot*8192

  // B global base: row = colBase + wn*64 + l15 (+ nf*16), col = lhi*8 (+ k0)
  const bf16_t* bP = Bw + (size_t)(colBase + wn * 64 + l15) * ldb + lhi * 8;
  const size_t bNf = (size_t)16 * ldb;

  const int nt = K >> 5;    // K in {512,2048,3072} -> nt 16/64/96 (even, >=16)

  f32x4 acc[8][4] = {};
  bf16x8 bE[4], bO[4];

  #define STAGE_A(kt, s)                                                            \
    do {                                                                            \
      const bf16_t* a_ = aS + (size_t)(kt) * 32;                                    \
      bf16_t* da_ = daW + (s) * 8192;                                               \
      __builtin_amdgcn_global_load_lds(AS1(a_),      AS3(da_),        16, 0, 0);    \
      __builtin_amdgcn_global_load_lds(AS1(a_ + aI), AS3(da_ + 4096), 16, 0, 0);    \
    } while (0)

  #define LOADB(kt, BR)                                                             \
    do {                                                                            \
      const bf16_t* p_ = bP + (size_t)(kt) * 32;                                    \
      BR[0] = *(const bf16x8*)(p_);                                                 \
      BR[1] = *(const bf16x8*)(p_ + bNf);                                           \
      BR[2] = *(const bf16x8*)(p_ + 2 * bNf);                                       \
      BR[3] = *(const bf16x8*)(p_ + 3 * bNf);                                       \
    } while (0)

  #define MFMAC(AF, BR)                                                             \
    do {                                                                            \
      __builtin_amdgcn_s_setprio(1);                                                \
      _Pragma("unroll")                                                             \
      for (int mf_ = 0; mf_ < 8; ++mf_)                                             \
        _Pragma("unroll")                                                           \
        for (int nf_ = 0; nf_ < 4; ++nf_)                                           \
          acc[mf_][nf_] = __builtin_amdgcn_mfma_f32_16x16x32_bf16(                  \
              AF[mf_], BR[nf_], acc[mf_][nf_], 0, 0, 0);                            \
      __builtin_amdgcn_s_setprio(0);                                                \
    } while (0)

  #define DRAIN_BAR()                                                               \
    do {                                                                            \
      asm volatile("s_waitcnt vmcnt(0)" ::: "memory");                              \
      asm volatile("s_waitcnt lgkmcnt(0)" ::: "memory");                            \
      __builtin_amdgcn_s_barrier();                                                 \
      asm volatile("" ::: "memory");                                                \
    } while (0)

  // prologue: stage A tiles 0..2, load B(0); full drain + barrier.
  STAGE_A(0, 0); STAGE_A(1, 1); STAGE_A(2, 2);
  LOADB(0, bE);
  DRAIN_BAR();

  for (int j = 0; j < nt; j += 2) {
    // ---- tile j (even): consume bE, prefetch B(j+1)->bO, stage A(j+3) ----
    {
      const int s = j & 3;
      const bf16_t* As_ = Ab + s * 8192 + aOff;
      bf16x8 af[8];
      #pragma unroll
      for (int mf = 0; mf < 8; ++mf) af[mf] = *(const bf16x8*)(As_ + mf * 512);
      if (j + 3 < nt) STAGE_A(j + 3, ((j + 3) & 3));
      LOADB(j + 1, bO);
      MFMAC(af, bE);
      DRAIN_BAR();
    }
    // ---- tile j+1 (odd): consume bO, prefetch B(j+2)->bE, stage A(j+4) ----
    {
      const int s = (j + 1) & 3;
      const bf16_t* As_ = Ab + s * 8192 + aOff;
      bf16x8 af[8];
      #pragma unroll
      for (int mf = 0; mf < 8; ++mf) af[mf] = *(const bf16x8*)(As_ + mf * 512);
      if (j + 4 < nt) STAGE_A(j + 4, ((j + 4) & 3));
      if (j + 2 < nt) LOADB(j + 2, bE);
      MFMAC(af, bO);
      if (j + 2 < nt) DRAIN_BAR();
      // last tile: no further LDS use, fall to epilogue
    }
  }
  #undef STAGE_A
  #undef LOADB
  #undef MFMAC
  #undef DRAIN_BAR

  // epilogue: C/D layout col=l15, row=lhi*4+i (verified)
  #pragma unroll
  for (int mf = 0; mf < 8; ++mf) {
    const int row = rowBase + wm * 128 + mf * 16 + lhi * 4;
    #pragma unroll
    for (int nf = 0; nf < 4; ++nf) {
      const int col = colBase + wn * 64 + nf * 16 + l15;
      const float bv = (col < Nmask) ? bias[col] : 0.0f;
      #pragma unroll
      for (int i = 0; i < 4; ++i) {
        float v = acc[mf][nf][i] + bv;
        if (RELU) v = fmaxf(v, 0.0f);
        if (OUT_BF16) {
          ((bf16_t*)Cout)[(size_t)(row + i) * ldc + col] = (bf16_t)v;
        } else {
          if (col < Nmask) ((float*)Cout)[(size_t)(row + i) * ldc + col] = v;
        }
      }
    }
  }
}

// ---------------- alphas -> softmax -> context (one block per row) ----------------
__global__ __launch_bounds__(256)
void attn_ctx(const bf16_t* __restrict__ P, bf16_t* __restrict__ ds) {
  __shared__ float red[3][4];
  __shared__ float wsh[3];
  const int r = blockIdx.x;
  const int t = threadIdx.x;
  const bf16_t* Prow = P + (size_t)r * 3072;
  bf16_t* dsrow = ds + (size_t)r * 2048;

  const int j = t * 4;
  bf16x4 lv = *(const bf16x4*)(dsrow + 1024 + j);
  float lhv[4], pv[3][4];
  float s[3] = {0.f, 0.f, 0.f};
  #pragma unroll
  for (int q = 0; q < 4; q++) lhv[q] = (float)lv[q];
  #pragma unroll
  for (int e = 0; e < 3; e++) {
    bf16x4 p = *(const bf16x4*)(Prow + e * 1024 + j);
    #pragma unroll
    for (int q = 0; q < 4; q++) {
      pv[e][q] = (float)p[q];
      s[e] += lhv[q] * pv[e][q];
    }
  }
  #pragma unroll
  for (int off = 32; off > 0; off >>= 1) {
    #pragma unroll
    for (int e = 0; e < 3; e++) s[e] += __shfl_down(s[e], off, 64);
  }
  const int w = t >> 6, l = t & 63;
  if (l == 0) {
    #pragma unroll
    for (int e = 0; e < 3; e++) red[e][w] = s[e];
  }
  __syncthreads();
  if (t == 0) {
    float a0 = red[0][0] + red[0][1] + red[0][2] + red[0][3];
    float a1 = red[1][0] + red[1][1] + red[1][2] + red[1][3];
    float a2 = red[2][0] + red[2][1] + red[2][2] + red[2][3];
    float mx = fmaxf(a0, fmaxf(a1, a2));
    float e0 = expf(a0 - mx), e1 = expf(a1 - mx), e2 = expf(a2 - mx);
    float inv = 1.0f / (e0 + e1 + e2);
    wsh[0] = e0 * inv; wsh[1] = e1 * inv; wsh[2] = e2 * inv;
  }
  __syncthreads();
  const float w0 = wsh[0], w1 = wsh[1], w2 = wsh[2];
  bf16x4 o;
  #pragma unroll
  for (int q = 0; q < 4; q++)
    o[q] = (bf16_t)(w0 * pv[0][q] + w1 * pv[1][q] + w2 * pv[2][q]);
  *(bf16x4*)(dsrow + j) = o;
}

// ---------------- launch ----------------
extern "C" void kernel_launch(void* const* d_in, const int* in_sizes, int n_in,
                              void* d_out, int out_size, void* d_ws, size_t ws_size,
                              hipStream_t stream) {
  (void)in_sizes; (void)n_in; (void)out_size; (void)ws_size;

  const float* tube = (const float*)d_in[0];
  const float* w1W  = (const float*)d_in[1];
  const float* w1b  = (const float*)d_in[2];
  const float* w2W  = (const float*)d_in[3];
  const float* w2b  = (const float*)d_in[4];
  const float* w3W  = (const float*)d_in[5];
  const float* w3b  = (const float*)d_in[6];
  const float* whW  = (const float*)d_in[7];
  const float* whb  = (const float*)d_in[8];
  const float* wd1W = (const float*)d_in[9];
  const float* wd1b = (const float*)d_in[10];
  const float* wd2W = (const float*)d_in[11];
  const float* wd2b = (const float*)d_in[12];

  // workspace layout (bytes); out1 aliases {whB, w123B, tubeB} which are dead by G4.
  char* ws = (char*)d_ws;
  bf16_t* P       = (bf16_t*)(ws + 0);            // 16384x3072
  bf16_t* ds      = (bf16_t*)(ws + 100663296);    // 16384x2048
  bf16_t* wd1B    = (bf16_t*)(ws + 167772160);    // 2048x2048
  bf16_t* wd2B    = (bf16_t*)(ws + 176160768);    // 1024x2048 (rows 1000.. zero)
  bf16_t* whB     = (bf16_t*)(ws + 180355072);    // 1024x3072
  bf16_t* w123B   = (bf16_t*)(ws + 186646528);    // 3072x512
  bf16_t* tubeB   = (bf16_t*)(ws + 189792256);    // 16384x1536
  bf16_t* out1    = (bf16_t*)(ws + 180355072);    // 16384x2048, aliases whB..tubeB
  float*  bias123 = (float*)(ws + 247463936);     // 3072 f32

  hipFuncSetAttribute((const void*)(gemm256<true,  true,  true >),
                      hipFuncAttributeMaxDynamicSharedMemorySize, 65536);
  hipFuncSetAttribute((const void*)(gemm256<false, true,  true >),
                      hipFuncAttributeMaxDynamicSharedMemorySize, 65536);
  hipFuncSetAttribute((const void*)(gemm256<false, false, false>),
                      hipFuncAttributeMaxDynamicSharedMemorySize, 65536);

  // conversions: tube (big, separate) + all weights (one launch)
  hipLaunchKernelGGL(cvt_f32_bf16_v4, dim3(2048), dim3(256), 0, stream,
                     tube, tubeB, 6291456, 6291456);
  hipLaunchKernelGGL(cvt_weights, dim3(2048), dim3(256), 0, stream,
                     w1W, w2W, w3W, whW, wd1W, wd2W, w123B, whB, wd1B, wd2B);
  hipLaunchKernelGGL(concat_bias3, dim3(12), dim3(256), 0, stream, w1b, w2b, w3b, bias123);

  // G1: P = relu(block-diag expert GEMM), N=3072, K=512
  hipLaunchKernelGGL((gemm256<true, true, true>), dim3(12 * 64), dim3(512), 65536, stream,
                     tubeB, 1536, w123B, 512, bias123, (void*)P, 3072, 512, 3072, 12);
  // G2: ds[:,1024:2048] = relu(P @ wh^T + b), N=1024, K=3072
  hipLaunchKernelGGL((gemm256<false, true, true>), dim3(4 * 64), dim3(512), 65536, stream,
                     P, 3072, whB, 3072, whb, (void*)(ds + 1024), 2048, 3072, 1024, 4);
  // attn: alphas -> softmax -> context into ds[:,0:1024]
  hipLaunchKernelGGL(attn_ctx, dim3(16384), dim3(256), 0, stream, P, ds);
  // G4: out1 = relu(ds @ wd1^T + b), N=2048, K=2048
  hipLaunchKernelGGL((gemm256<false, true, true>), dim3(8 * 64), dim3(512), 65536, stream,
                     ds, 2048, wd1B, 2048, wd1b, (void*)out1, 2048, 2048, 2048, 8);
  // G5: out = out1 @ wd2^T + b (fp32, N masked to 1000), K=2048
  hipLaunchKernelGGL((gemm256<false, false, false>), dim3(4 * 64), dim3(512), 65536, stream,
                     out1, 2048, wd2B, 2048, wd2b, d_out, 1000, 2048, 1000, 4);
}

// Round 12
// 586.953 us; speedup vs baseline: 1.0584x; 1.0584x over previous
//
#include <hip/hip_runtime.h>
#include <hip/hip_bf16.h>

// ClassAtt fused pipeline. R12 = R10 (B operand in registers, A-only 4-slot
// LDS ring, counted vmcnt) with the prologue wait fixed vmcnt(8)->vmcnt(4).
// Ledger re-verified under worst-case intra-iteration reordering of the
// compiler-scheduled B loads vs the STAGE_A builtins (loads cannot cross the
// "memory"-clobber asm at iteration boundaries):
//   prologue: issue {A0,A1,A2,B0} any order -> vmcnt(4) retires >=6 oldest,
//             which always includes both A(0) loads.            [was the bug]
//   steady even/odd: >=12 loads provably newer than A(j+1)/A(j+2) -> vmcnt(8).
//   tails: vmcnt(4) (j=nt-2) and vmcnt(6) (j=nt-4) re-checked likewise.

typedef __bf16 bf16_t;
typedef __bf16 bf16x4 __attribute__((ext_vector_type(4)));
typedef __bf16 bf16x8 __attribute__((ext_vector_type(8)));
typedef float  f32x4  __attribute__((ext_vector_type(4)));

#define AS1(p) (const __attribute__((address_space(1))) void*)(p)
#define AS3(p) (__attribute__((address_space(3))) void*)(p)

// ---------------- f32 -> bf16 conversion (tube) ----------------
__global__ void cvt_f32_bf16_v4(const float* __restrict__ src, bf16_t* __restrict__ dst,
                                int n4src, int n4tot) {
  for (int i = blockIdx.x * blockDim.x + threadIdx.x; i < n4tot; i += gridDim.x * blockDim.x) {
    bf16x4 o;
    if (i < n4src) {
      float4 f = ((const float4*)src)[i];
      o[0] = (bf16_t)f.x; o[1] = (bf16_t)f.y; o[2] = (bf16_t)f.z; o[3] = (bf16_t)f.w;
    } else {
      o[0] = (bf16_t)0.0f; o[1] = (bf16_t)0.0f; o[2] = (bf16_t)0.0f; o[3] = (bf16_t)0.0f;
    }
    *(bf16x4*)(dst + (size_t)i * 4) = o;
  }
}

// ---------------- all weight cvts merged (one launch) ----------------
__global__ void cvt_weights(const float* __restrict__ w1, const float* __restrict__ w2,
                            const float* __restrict__ w3, const float* __restrict__ wh,
                            const float* __restrict__ wd1, const float* __restrict__ wd2,
                            bf16_t* __restrict__ w123, bf16_t* __restrict__ whB,
                            bf16_t* __restrict__ wd1B, bf16_t* __restrict__ wd2B) {
  const int stride = gridDim.x * blockDim.x;
  for (int i = blockIdx.x * blockDim.x + threadIdx.x; i < 2752512; i += stride) {
    const float* s; bf16_t* d; int o; int ns = 1 << 30;
    if (i < 131072)       { s = w1;  d = w123;           o = i; }
    else if (i < 262144)  { s = w2;  d = w123 + 524288;  o = i - 131072; }
    else if (i < 393216)  { s = w3;  d = w123 + 1048576; o = i - 262144; }
    else if (i < 1179648) { s = wh;  d = whB;            o = i - 393216; }
    else if (i < 2228224) { s = wd1; d = wd1B;           o = i - 1179648; }
    else                  { s = wd2; d = wd2B;           o = i - 2228224; ns = 512000; }
    bf16x4 v;
    if (o < ns) {
      float4 f = ((const float4*)s)[o];
      v[0] = (bf16_t)f.x; v[1] = (bf16_t)f.y; v[2] = (bf16_t)f.z; v[3] = (bf16_t)f.w;
    } else {
      v[0] = (bf16_t)0.0f; v[1] = (bf16_t)0.0f; v[2] = (bf16_t)0.0f; v[3] = (bf16_t)0.0f;
    }
    *(bf16x4*)(d + (size_t)o * 4) = v;
  }
}

__global__ void concat_bias3(const float* __restrict__ a, const float* __restrict__ b,
                             const float* __restrict__ c, float* __restrict__ dst) {
  int i = blockIdx.x * blockDim.x + threadIdx.x;
  if (i < 1024) dst[i] = a[i];
  else if (i < 2048) dst[i] = b[i - 1024];
  else if (i < 3072) dst[i] = c[i - 2048];
}

// ---------------- GEMM: C = act(A @ Bw^T + bias), 256x256 tile ----------------
// 512 threads = 8 waves (2M x 4N), wave tile 128x64 = acc[8][4] 16x16 frags.
// A: LDS 4-slot ring (64 KiB dynamic), R2 staging + XOR swizzle (conflict-free).
// B: global->VGPR (element-identical to the verified LDS path), bE/bO
// double-buffer, prefetched 1 tile ahead. Counted vmcnt per ledger above.
template<bool BDIAG, bool RELU, bool OUT_BF16>
__global__ __launch_bounds__(512, 2)
void gemm256(const bf16_t* __restrict__ A, int lda,
             const bf16_t* __restrict__ Bw, int ldb,
             const float* __restrict__ bias,
             void* __restrict__ Cout, int ldc,
             int K, int Nmask, int nbx)
{
  extern __shared__ char lds[];
  bf16_t* Ab = (bf16_t*)lds;               // 4 slots x 8192 elems (16 KiB/slot)

  const int t   = threadIdx.x;
  const int ln  = t & 63;
  const int w   = t >> 6;
  const int l15 = ln & 15, lhi = ln >> 4;
  const int wm  = w >> 2, wn = w & 3;

  // XCD-chunked block swizzle (grid divisible by 8)
  const int nb = (int)gridDim.x;
  const int id = (int)blockIdx.x;
  const int id_sw = (id & 7) * (nb >> 3) + (id >> 3);
  const int bx = id_sw % nbx, by = id_sw / nbx;
  const int rowBase = by * 256;
  const int colBase = bx * 256;
  const int aCol0 = BDIAG ? (colBase >> 10) * 512 : 0;

  // A staging (R2-verified): thread t -> LDS row i*128 + w*16 + ln/4, linear
  // 16B dest; source granule pre-swizzled with key=(row>>1)&3 involution.
  const int srow = (w << 4) + (ln >> 2);
  const int scol = (((ln & 3) ^ (ln >> 3)) & 3) << 3;
  const bf16_t* aS = A + (size_t)(rowBase + srow) * lda + aCol0 + scol;
  const size_t aI = (size_t)128 * lda;
  bf16_t* daW = Ab + (w << 9);

  // A fragment read offsets (elements), swizzle involution re-applied
  const int key  = (l15 >> 1) & 3;
  const int fcol = (lhi ^ key) << 3;
  const int aOff = (wm * 128 + l15) * 32 + fcol;   // + mf*512 + slot*8192

  // B global base: row = colBase + wn*64 + l15 (+ nf*16), col = lhi*8 (+ k0)
  const bf16_t* bP = Bw + (size_t)(colBase + wn * 64 + l15) * ldb + lhi * 8;
  const size_t bNf = (size_t)16 * ldb;

  const int nt = K >> 5;    // K in {512,2048,3072} -> nt 16/64/96 (even, >=16)

  f32x4 acc[8][4] = {};
  bf16x8 bE[4], bO[4];

  #define STAGE_A(kt, s)                                                            \
    do {                                                                            \
      const bf16_t* a_ = aS + (size_t)(kt) * 32;                                    \
      bf16_t* da_ = daW + (s) * 8192;                                               \
      __builtin_amdgcn_global_load_lds(AS1(a_),      AS3(da_),        16, 0, 0);    \
      __builtin_amdgcn_global_load_lds(AS1(a_ + aI), AS3(da_ + 4096), 16, 0, 0);    \
    } while (0)

  #define LOADB(kt, BR)                                                             \
    do {                                                                            \
      const bf16_t* p_ = bP + (size_t)(kt) * 32;                                    \
      BR[0] = *(const bf16x8*)(p_);                                                 \
      BR[1] = *(const bf16x8*)(p_ + bNf);                                           \
      BR[2] = *(const bf16x8*)(p_ + 2 * bNf);                                       \
      BR[3] = *(const bf16x8*)(p_ + 3 * bNf);                                       \
    } while (0)

  #define MFMAC(AF, BR)                                                             \
    do {                                                                            \
      __builtin_amdgcn_s_setprio(1);                                                \
      _Pragma("unroll")                                                             \
      for (int mf_ = 0; mf_ < 8; ++mf_)                                             \
        _Pragma("unroll")                                                           \
        for (int nf_ = 0; nf_ < 4; ++nf_)                                           \
          acc[mf_][nf_] = __builtin_amdgcn_mfma_f32_16x16x32_bf16(                  \
              AF[mf_], BR[nf_], acc[mf_][nf_], 0, 0, 0);                            \
      __builtin_amdgcn_s_setprio(0);                                                \
    } while (0)

  // prologue: stage A tiles 0..2 (6 lds-loads) + B(0) (4 reg-loads).
  // vmcnt(4): retires >=6 oldest of the 10 regardless of intra-block load
  // order -> A(0) provably arrived. [R10 bug fix]
  STAGE_A(0, 0); STAGE_A(1, 1); STAGE_A(2, 2);
  LOADB(0, bE);
  asm volatile("s_waitcnt vmcnt(4)" ::: "memory");
  __builtin_amdgcn_s_barrier();
  asm volatile("" ::: "memory");

  for (int j = 0; j < nt; j += 2) {
    // ---- tile j (even): consume bE, prefetch B(j+1)->bO, stage A(j+3) ----
    {
      const int s = j & 3;
      const bf16_t* As_ = Ab + s * 8192 + aOff;
      bf16x8 af[8];
      #pragma unroll
      for (int mf = 0; mf < 8; ++mf) af[mf] = *(const bf16x8*)(As_ + mf * 512);
      if (j + 3 < nt) STAGE_A(j + 3, ((j + 3) & 3));
      LOADB(j + 1, bO);
      MFMAC(af, bE);
      // A(j+1) staged >=2 iterations back: >=10 loads provably newer under
      // any intra-iteration order -> vmcnt(8) safe. Tail j=nt-2: B(j+1) is
      // the only current-iter issue -> vmcnt(4).
      if (j + 3 < nt) { asm volatile("s_waitcnt vmcnt(8)" ::: "memory"); }
      else            { asm volatile("s_waitcnt vmcnt(4)" ::: "memory"); }
      asm volatile("s_waitcnt lgkmcnt(0)" ::: "memory");
      __builtin_amdgcn_s_barrier();
      asm volatile("" ::: "memory");
    }
    // ---- tile j+1 (odd): consume bO, prefetch B(j+2)->bE, stage A(j+4) ----
    {
      const int s = (j + 1) & 3;
      const bf16_t* As_ = Ab + s * 8192 + aOff;
      bf16x8 af[8];
      #pragma unroll
      for (int mf = 0; mf < 8; ++mf) af[mf] = *(const bf16x8*)(As_ + mf * 512);
      if (j + 4 < nt) STAGE_A(j + 4, ((j + 4) & 3));
      if (j + 2 < nt) LOADB(j + 2, bE);
      MFMAC(af, bO);
      if (j + 4 < nt) {
        asm volatile("s_waitcnt vmcnt(8)" ::: "memory");
        asm volatile("s_waitcnt lgkmcnt(0)" ::: "memory");
        __builtin_amdgcn_s_barrier();
        asm volatile("" ::: "memory");
      } else if (j + 2 < nt) {
        // j = nt-4: newer-than-A(j+2) >= {A(nt-1)2 + B(nt-3)4 + B(nt-2)4}
        // minus ordering slack -> vmcnt(6) still drains A(j+2) (re-checked).
        asm volatile("s_waitcnt vmcnt(6)" ::: "memory");
        asm volatile("s_waitcnt lgkmcnt(0)" ::: "memory");
        __builtin_amdgcn_s_barrier();
        asm volatile("" ::: "memory");
      }
      // else: last tile — no further LDS use, fall to epilogue
    }
  }
  #undef STAGE_A
  #undef LOADB
  #undef MFMAC

  // epilogue: C/D layout col=l15, row=lhi*4+i (verified)
  #pragma unroll
  for (int mf = 0; mf < 8; ++mf) {
    const int row = rowBase + wm * 128 + mf * 16 + lhi * 4;
    #pragma unroll
    for (int nf = 0; nf < 4; ++nf) {
      const int col = colBase + wn * 64 + nf * 16 + l15;
      const float bv = (col < Nmask) ? bias[col] : 0.0f;
      #pragma unroll
      for (int i = 0; i < 4; ++i) {
        float v = acc[mf][nf][i] + bv;
        if (RELU) v = fmaxf(v, 0.0f);
        if (OUT_BF16) {
          ((bf16_t*)Cout)[(size_t)(row + i) * ldc + col] = (bf16_t)v;
        } else {
          if (col < Nmask) ((float*)Cout)[(size_t)(row + i) * ldc + col] = v;
        }
      }
    }
  }
}

// ---------------- alphas -> softmax -> context (one block per row) ----------------
__global__ __launch_bounds__(256)
void attn_ctx(const bf16_t* __restrict__ P, bf16_t* __restrict__ ds) {
  __shared__ float red[3][4];
  __shared__ float wsh[3];
  const int r = blockIdx.x;
  const int t = threadIdx.x;
  const bf16_t* Prow = P + (size_t)r * 3072;
  bf16_t* dsrow = ds + (size_t)r * 2048;

  const int j = t * 4;
  bf16x4 lv = *(const bf16x4*)(dsrow + 1024 + j);
  float lhv[4], pv[3][4];
  float s[3] = {0.f, 0.f, 0.f};
  #pragma unroll
  for (int q = 0; q < 4; q++) lhv[q] = (float)lv[q];
  #pragma unroll
  for (int e = 0; e < 3; e++) {
    bf16x4 p = *(const bf16x4*)(Prow + e * 1024 + j);
    #pragma unroll
    for (int q = 0; q < 4; q++) {
      pv[e][q] = (float)p[q];
      s[e] += lhv[q] * pv[e][q];
    }
  }
  #pragma unroll
  for (int off = 32; off > 0; off >>= 1) {
    #pragma unroll
    for (int e = 0; e < 3; e++) s[e] += __shfl_down(s[e], off, 64);
  }
  const int w = t >> 6, l = t & 63;
  if (l == 0) {
    #pragma unroll
    for (int e = 0; e < 3; e++) red[e][w] = s[e];
  }
  __syncthreads();
  if (t == 0) {
    float a0 = red[0][0] + red[0][1] + red[0][2] + red[0][3];
    float a1 = red[1][0] + red[1][1] + red[1][2] + red[1][3];
    float a2 = red[2][0] + red[2][1] + red[2][2] + red[2][3];
    float mx = fmaxf(a0, fmaxf(a1, a2));
    float e0 = expf(a0 - mx), e1 = expf(a1 - mx), e2 = expf(a2 - mx);
    float inv = 1.0f / (e0 + e1 + e2);
    wsh[0] = e0 * inv; wsh[1] = e1 * inv; wsh[2] = e2 * inv;
  }
  __syncthreads();
  const float w0 = wsh[0], w1 = wsh[1], w2 = wsh[2];
  bf16x4 o;
  #pragma unroll
  for (int q = 0; q < 4; q++)
    o[q] = (bf16_t)(w0 * pv[0][q] + w1 * pv[1][q] + w2 * pv[2][q]);
  *(bf16x4*)(dsrow + j) = o;
}

// ---------------- launch ----------------
extern "C" void kernel_launch(void* const* d_in, const int* in_sizes, int n_in,
                              void* d_out, int out_size, void* d_ws, size_t ws_size,
                              hipStream_t stream) {
  (void)in_sizes; (void)n_in; (void)out_size; (void)ws_size;

  const float* tube = (const float*)d_in[0];
  const float* w1W  = (const float*)d_in[1];
  const float* w1b  = (const float*)d_in[2];
  const float* w2W  = (const float*)d_in[3];
  const float* w2b  = (const float*)d_in[4];
  const float* w3W  = (const float*)d_in[5];
  const float* w3b  = (const float*)d_in[6];
  const float* whW  = (const float*)d_in[7];
  const float* whb  = (const float*)d_in[8];
  const float* wd1W = (const float*)d_in[9];
  const float* wd1b = (const float*)d_in[10];
  const float* wd2W = (const float*)d_in[11];
  const float* wd2b = (const float*)d_in[12];

  // workspace layout (bytes); out1 aliases {whB, w123B, tubeB} which are dead by G4.
  char* ws = (char*)d_ws;
  bf16_t* P       = (bf16_t*)(ws + 0);            // 16384x3072
  bf16_t* ds      = (bf16_t*)(ws + 100663296);    // 16384x2048
  bf16_t* wd1B    = (bf16_t*)(ws + 167772160);    // 2048x2048
  bf16_t* wd2B    = (bf16_t*)(ws + 176160768);    // 1024x2048 (rows 1000.. zero)
  bf16_t* whB     = (bf16_t*)(ws + 180355072);    // 1024x3072
  bf16_t* w123B   = (bf16_t*)(ws + 186646528);    // 3072x512
  bf16_t* tubeB   = (bf16_t*)(ws + 189792256);    // 16384x1536
  bf16_t* out1    = (bf16_t*)(ws + 180355072);    // 16384x2048, aliases whB..tubeB
  float*  bias123 = (float*)(ws + 247463936);     // 3072 f32

  hipFuncSetAttribute((const void*)(gemm256<true,  true,  true >),
                      hipFuncAttributeMaxDynamicSharedMemorySize, 65536);
  hipFuncSetAttribute((const void*)(gemm256<false, true,  true >),
                      hipFuncAttributeMaxDynamicSharedMemorySize, 65536);
  hipFuncSetAttribute((const void*)(gemm256<false, false, false>),
                      hipFuncAttributeMaxDynamicSharedMemorySize, 65536);

  // conversions: tube (big, separate) + all weights (one launch)
  hipLaunchKernelGGL(cvt_f32_bf16_v4, dim3(2048), dim3(256), 0, stream,
                     tube, tubeB, 6291456, 6291456);
  hipLaunchKernelGGL(cvt_weights, dim3(2048), dim3(256), 0, stream,
                     w1W, w2W, w3W, whW, wd1W, wd2W, w123B, whB, wd1B, wd2B);
  hipLaunchKernelGGL(concat_bias3, dim3(12), dim3(256), 0, stream, w1b, w2b, w3b, bias123);

  // G1: P = relu(block-diag expert GEMM), N=3072, K=512
  hipLaunchKernelGGL((gemm256<true, true, true>), dim3(12 * 64), dim3(512), 65536, stream,
                     tubeB, 1536, w123B, 512, bias123, (void*)P, 3072, 512, 3072, 12);
  // G2: ds[:,1024:2048] = relu(P @ wh^T + b), N=1024, K=3072
  hipLaunchKernelGGL((gemm256<false, true, true>), dim3(4 * 64), dim3(512), 65536, stream,
                     P, 3072, whB, 3072, whb, (void*)(ds + 1024), 2048, 3072, 1024, 4);
  // attn: alphas -> softmax -> context into ds[:,0:1024]
  hipLaunchKernelGGL(attn_ctx, dim3(16384), dim3(256), 0, stream, P, ds);
  // G4: out1 = relu(ds @ wd1^T + b), N=2048, K=2048
  hipLaunchKernelGGL((gemm256<false, true, true>), dim3(8 * 64), dim3(512), 65536, stream,
                     ds, 2048, wd1B, 2048, wd1b, (void*)out1, 2048, 2048, 2048, 8);
  // G5: out = out1 @ wd2^T + b (fp32, N masked to 1000), K=2048
  hipLaunchKernelGGL((gemm256<false, false, false>), dim3(4 * 64), dim3(512), 65536, stream,
                     out1, 2048, wd2B, 2048, wd2b, d_out, 1000, 2048, 1000, 4);
}

// Round 13
// 416.706 us; speedup vs baseline: 1.4908x; 1.4086x over previous
//
#include <hip/hip_runtime.h>
#include <hip/hip_bf16.h>

// ClassAtt fused pipeline. R13 = R2 GEMM verbatim (best measured: 256x256
// tile, BK=32, 4-slot ring staging counted vmcnt(8), XOR swizzle conflicts=0,
// XCD swizzle, 16x16x32 MFMA, reads->bar->MFMA order) + merged weight cvt.

typedef __bf16 bf16_t;
typedef __bf16 bf16x4 __attribute__((ext_vector_type(4)));
typedef __bf16 bf16x8 __attribute__((ext_vector_type(8)));
typedef float  f32x4  __attribute__((ext_vector_type(4)));

#define AS1(p) (const __attribute__((address_space(1))) void*)(p)
#define AS3(p) (__attribute__((address_space(3))) void*)(p)

// ---------------- f32 -> bf16 conversion (tube) ----------------
__global__ void cvt_f32_bf16_v4(const float* __restrict__ src, bf16_t* __restrict__ dst,
                                int n4src, int n4tot) {
  for (int i = blockIdx.x * blockDim.x + threadIdx.x; i < n4tot; i += gridDim.x * blockDim.x) {
    bf16x4 o;
    if (i < n4src) {
      float4 f = ((const float4*)src)[i];
      o[0] = (bf16_t)f.x; o[1] = (bf16_t)f.y; o[2] = (bf16_t)f.z; o[3] = (bf16_t)f.w;
    } else {
      o[0] = (bf16_t)0.0f; o[1] = (bf16_t)0.0f; o[2] = (bf16_t)0.0f; o[3] = (bf16_t)0.0f;
    }
    *(bf16x4*)(dst + (size_t)i * 4) = o;
  }
}

// ---------------- all weight cvts merged (one launch; verified R9/R12) ----------
__global__ void cvt_weights(const float* __restrict__ w1, const float* __restrict__ w2,
                            const float* __restrict__ w3, const float* __restrict__ wh,
                            const float* __restrict__ wd1, const float* __restrict__ wd2,
                            bf16_t* __restrict__ w123, bf16_t* __restrict__ whB,
                            bf16_t* __restrict__ wd1B, bf16_t* __restrict__ wd2B) {
  const int stride = gridDim.x * blockDim.x;
  for (int i = blockIdx.x * blockDim.x + threadIdx.x; i < 2752512; i += stride) {
    const float* s; bf16_t* d; int o; int ns = 1 << 30;
    if (i < 131072)       { s = w1;  d = w123;           o = i; }
    else if (i < 262144)  { s = w2;  d = w123 + 524288;  o = i - 131072; }
    else if (i < 393216)  { s = w3;  d = w123 + 1048576; o = i - 262144; }
    else if (i < 1179648) { s = wh;  d = whB;            o = i - 393216; }
    else if (i < 2228224) { s = wd1; d = wd1B;           o = i - 1179648; }
    else                  { s = wd2; d = wd2B;           o = i - 2228224; ns = 512000; }
    bf16x4 v;
    if (o < ns) {
      float4 f = ((const float4*)s)[o];
      v[0] = (bf16_t)f.x; v[1] = (bf16_t)f.y; v[2] = (bf16_t)f.z; v[3] = (bf16_t)f.w;
    } else {
      v[0] = (bf16_t)0.0f; v[1] = (bf16_t)0.0f; v[2] = (bf16_t)0.0f; v[3] = (bf16_t)0.0f;
    }
    *(bf16x4*)(d + (size_t)o * 4) = v;
  }
}

__global__ void concat_bias3(const float* __restrict__ a, const float* __restrict__ b,
                             const float* __restrict__ c, float* __restrict__ dst) {
  int i = blockIdx.x * blockDim.x + threadIdx.x;
  if (i < 1024) dst[i] = a[i];
  else if (i < 2048) dst[i] = b[i - 1024];
  else if (i < 3072) dst[i] = c[i - 2048];
}

// ---------------- GEMM: C = act(A @ Bw^T + bias), 256x256 tile, pipelined ----------------
// 512 threads = 8 waves (2 M x 4 N), each wave owns a 128x64 output sub-tile
// (acc[8][4] of 16x16 frags). LDS: 4-slot ring of (A 256x32 + B 256x32) bf16
// = 128 KiB dynamic. Stage tile j+3 while computing tile j; steady wait vmcnt(8).
// (R2-verified structure: best of 10 measured schedule variants.)
template<bool BDIAG, bool RELU, bool OUT_BF16>
__global__ __launch_bounds__(512, 2)
void gemm256(const bf16_t* __restrict__ A, int lda,
             const bf16_t* __restrict__ Bw, int ldb,
             const float* __restrict__ bias,
             void* __restrict__ Cout, int ldc,
             int K, int Nmask, int nbx)
{
  extern __shared__ char lds[];
  bf16_t* Ab = (bf16_t*)lds;               // 4 slots x 8192 elems (16 KiB/slot)
  bf16_t* Bb = (bf16_t*)(lds + 65536);

  const int t   = threadIdx.x;
  const int ln  = t & 63;
  const int w   = t >> 6;
  const int l15 = ln & 15, lhi = ln >> 4;
  const int wm  = w >> 2, wn = w & 3;

  // XCD-chunked block swizzle (grid divisible by 8)
  const int nb = (int)gridDim.x;
  const int id = (int)blockIdx.x;
  const int id_sw = (id & 7) * (nb >> 3) + (id >> 3);
  const int bx = id_sw % nbx, by = id_sw / nbx;
  const int rowBase = by * 256;
  const int colBase = bx * 256;
  const int aCol0 = BDIAG ? (colBase >> 10) * 512 : 0;

  // staging: thread t -> LDS linear byte i*8192 + w*1024 + ln*16
  //   (row = i*128 + w*16 + ln/4); source col granule pre-swizzled involution.
  const int srow = (w << 4) + (ln >> 2);
  const int scol = (((ln & 3) ^ (ln >> 3)) & 3) << 3;

  const bf16_t* aS = A  + (size_t)(rowBase + srow) * lda + aCol0 + scol;
  const bf16_t* bS = Bw + (size_t)(colBase + srow) * ldb + scol;
  const size_t aI = (size_t)128 * lda;
  const size_t bI = (size_t)128 * ldb;
  bf16_t* daW = Ab + (w << 9);
  bf16_t* dbW = Bb + (w << 9);

  // fragment read offsets (elements), swizzle involution re-applied
  const int key  = (l15 >> 1) & 3;
  const int fcol = (lhi ^ key) << 3;
  const int aOff = (wm * 128 + l15) * 32 + fcol;   // + mf*512 + slot*8192
  const int bOff = (wn * 64  + l15) * 32 + fcol;   // + nf*512 + slot*8192

  const int nt = K >> 5;

  f32x4 acc[8][4] = {};

  #define STAGE(kt, s)                                                              \
    do {                                                                            \
      const bf16_t* a_ = aS + (size_t)(kt) * 32;                                    \
      const bf16_t* b_ = bS + (size_t)(kt) * 32;                                    \
      bf16_t* da_ = daW + (s) * 8192;                                               \
      bf16_t* db_ = dbW + (s) * 8192;                                               \
      __builtin_amdgcn_global_load_lds(AS1(a_),      AS3(da_),        16, 0, 0);    \
      __builtin_amdgcn_global_load_lds(AS1(a_ + aI), AS3(da_ + 4096), 16, 0, 0);    \
      __builtin_amdgcn_global_load_lds(AS1(b_),      AS3(db_),        16, 0, 0);    \
      __builtin_amdgcn_global_load_lds(AS1(b_ + bI), AS3(db_ + 4096), 16, 0, 0);    \
    } while (0)

  // prologue: stage tiles 0..2, confirm tile 0 (8 = tiles 1,2 still in flight)
  STAGE(0, 0); STAGE(1, 1); STAGE(2, 2);
  asm volatile("s_waitcnt vmcnt(8)" ::: "memory");
  __builtin_amdgcn_s_barrier();
  asm volatile("" ::: "memory");

  for (int j = 0; j < nt; ++j) {
    const int s = j & 3;
    const bf16_t* As_ = Ab + s * 8192 + aOff;
    const bf16_t* Bs_ = Bb + s * 8192 + bOff;

    bf16x8 af[8], bfr[4];
    #pragma unroll
    for (int mf = 0; mf < 8; ++mf) af[mf] = *(const bf16x8*)(As_ + mf * 512);
    #pragma unroll
    for (int nf = 0; nf < 4; ++nf) bfr[nf] = *(const bf16x8*)(Bs_ + nf * 512);

    // prefetch tile j+3 into ring slot (j+3)&3 (slot read in phase j-1, drained)
    if (j + 3 < nt) {
      STAGE(j + 3, ((j + 3) & 3));
      asm volatile("s_waitcnt vmcnt(8)" ::: "memory");   // tile j+1 arrived
    } else if (j + 2 < nt) {
      asm volatile("s_waitcnt vmcnt(4)" ::: "memory");
    } else if (j + 1 < nt) {
      asm volatile("s_waitcnt vmcnt(0)" ::: "memory");
    }
    // drain own ds_reads BEFORE barrier (WAR fence for ring slot reuse)
    asm volatile("s_waitcnt lgkmcnt(0)" ::: "memory");
    __builtin_amdgcn_s_barrier();
    asm volatile("" ::: "memory");

    __builtin_amdgcn_s_setprio(1);
    #pragma unroll
    for (int mf = 0; mf < 8; ++mf)
      #pragma unroll
      for (int nf = 0; nf < 4; ++nf)
        acc[mf][nf] = __builtin_amdgcn_mfma_f32_16x16x32_bf16(af[mf], bfr[nf], acc[mf][nf], 0, 0, 0);
    __builtin_amdgcn_s_setprio(0);
  }
  #undef STAGE

  // epilogue: C/D layout col=l15, row=lhi*4+i (verified)
  #pragma unroll
  for (int mf = 0; mf < 8; ++mf) {
    const int row = rowBase + wm * 128 + mf * 16 + lhi * 4;
    #pragma unroll
    for (int nf = 0; nf < 4; ++nf) {
      const int col = colBase + wn * 64 + nf * 16 + l15;
      const float bv = (col < Nmask) ? bias[col] : 0.0f;
      #pragma unroll
      for (int i = 0; i < 4; ++i) {
        float v = acc[mf][nf][i] + bv;
        if (RELU) v = fmaxf(v, 0.0f);
        if (OUT_BF16) {
          ((bf16_t*)Cout)[(size_t)(row + i) * ldc + col] = (bf16_t)v;
        } else {
          if (col < Nmask) ((float*)Cout)[(size_t)(row + i) * ldc + col] = v;
        }
      }
    }
  }
}

// ---------------- alphas -> softmax -> context (one block per row) ----------------
__global__ __launch_bounds__(256)
void attn_ctx(const bf16_t* __restrict__ P, bf16_t* __restrict__ ds) {
  __shared__ float red[3][4];
  __shared__ float wsh[3];
  const int r = blockIdx.x;
  const int t = threadIdx.x;
  const bf16_t* Prow = P + (size_t)r * 3072;
  bf16_t* dsrow = ds + (size_t)r * 2048;

  const int j = t * 4;
  bf16x4 lv = *(const bf16x4*)(dsrow + 1024 + j);
  float lhv[4], pv[3][4];
  float s[3] = {0.f, 0.f, 0.f};
  #pragma unroll
  for (int q = 0; q < 4; q++) lhv[q] = (float)lv[q];
  #pragma unroll
  for (int e = 0; e < 3; e++) {
    bf16x4 p = *(const bf16x4*)(Prow + e * 1024 + j);
    #pragma unroll
    for (int q = 0; q < 4; q++) {
      pv[e][q] = (float)p[q];
      s[e] += lhv[q] * pv[e][q];
    }
  }
  #pragma unroll
  for (int off = 32; off > 0; off >>= 1) {
    #pragma unroll
    for (int e = 0; e < 3; e++) s[e] += __shfl_down(s[e], off, 64);
  }
  const int w = t >> 6, l = t & 63;
  if (l == 0) {
    #pragma unroll
    for (int e = 0; e < 3; e++) red[e][w] = s[e];
  }
  __syncthreads();
  if (t == 0) {
    float a0 = red[0][0] + red[0][1] + red[0][2] + red[0][3];
    float a1 = red[1][0] + red[1][1] + red[1][2] + red[1][3];
    float a2 = red[2][0] + red[2][1] + red[2][2] + red[2][3];
    float mx = fmaxf(a0, fmaxf(a1, a2));
    float e0 = expf(a0 - mx), e1 = expf(a1 - mx), e2 = expf(a2 - mx);
    float inv = 1.0f / (e0 + e1 + e2);
    wsh[0] = e0 * inv; wsh[1] = e1 * inv; wsh[2] = e2 * inv;
  }
  __syncthreads();
  const float w0 = wsh[0], w1 = wsh[1], w2 = wsh[2];
  bf16x4 o;
  #pragma unroll
  for (int q = 0; q < 4; q++)
    o[q] = (bf16_t)(w0 * pv[0][q] + w1 * pv[1][q] + w2 * pv[2][q]);
  *(bf16x4*)(dsrow + j) = o;
}

// ---------------- launch ----------------
extern "C" void kernel_launch(void* const* d_in, const int* in_sizes, int n_in,
                              void* d_out, int out_size, void* d_ws, size_t ws_size,
                              hipStream_t stream) {
  (void)in_sizes; (void)n_in; (void)out_size; (void)ws_size;

  const float* tube = (const float*)d_in[0];
  const float* w1W  = (const float*)d_in[1];
  const float* w1b  = (const float*)d_in[2];
  const float* w2W  = (const float*)d_in[3];
  const float* w2b  = (const float*)d_in[4];
  const float* w3W  = (const float*)d_in[5];
  const float* w3b  = (const float*)d_in[6];
  const float* whW  = (const float*)d_in[7];
  const float* whb  = (const float*)d_in[8];
  const float* wd1W = (const float*)d_in[9];
  const float* wd1b = (const float*)d_in[10];
  const float* wd2W = (const float*)d_in[11];
  const float* wd2b = (const float*)d_in[12];

  // workspace layout (bytes); out1 aliases {whB, w123B, tubeB} which are dead by G4.
  char* ws = (char*)d_ws;
  bf16_t* P       = (bf16_t*)(ws + 0);            // 16384x3072
  bf16_t* ds      = (bf16_t*)(ws + 100663296);    // 16384x2048
  bf16_t* wd1B    = (bf16_t*)(ws + 167772160);    // 2048x2048
  bf16_t* wd2B    = (bf16_t*)(ws + 176160768);    // 1024x2048 (rows 1000.. zero)
  bf16_t* whB     = (bf16_t*)(ws + 180355072);    // 1024x3072
  bf16_t* w123B   = (bf16_t*)(ws + 186646528);    // 3072x512
  bf16_t* tubeB   = (bf16_t*)(ws + 189792256);    // 16384x1536
  bf16_t* out1    = (bf16_t*)(ws + 180355072);    // 16384x2048, aliases whB..tubeB
  float*  bias123 = (float*)(ws + 247463936);     // 3072 f32

  // allow 128 KiB dynamic LDS for the gemm instantiations
  hipFuncSetAttribute((const void*)(gemm256<true,  true,  true >),
                      hipFuncAttributeMaxDynamicSharedMemorySize, 131072);
  hipFuncSetAttribute((const void*)(gemm256<false, true,  true >),
                      hipFuncAttributeMaxDynamicSharedMemorySize, 131072);
  hipFuncSetAttribute((const void*)(gemm256<false, false, false>),
                      hipFuncAttributeMaxDynamicSharedMemorySize, 131072);

  // conversions: tube (big, separate) + all weights (one launch)
  hipLaunchKernelGGL(cvt_f32_bf16_v4, dim3(2048), dim3(256), 0, stream,
                     tube, tubeB, 6291456, 6291456);
  hipLaunchKernelGGL(cvt_weights, dim3(2048), dim3(256), 0, stream,
                     w1W, w2W, w3W, whW, wd1W, wd2W, w123B, whB, wd1B, wd2B);
  hipLaunchKernelGGL(concat_bias3, dim3(12), dim3(256), 0, stream, w1b, w2b, w3b, bias123);

  // G1: P = relu(block-diag expert GEMM), N=3072, K=512
  hipLaunchKernelGGL((gemm256<true, true, true>), dim3(12 * 64), dim3(512), 131072, stream,
                     tubeB, 1536, w123B, 512, bias123, (void*)P, 3072, 512, 3072, 12);
  // G2: ds[:,1024:2048] = relu(P @ wh^T + b), N=1024, K=3072
  hipLaunchKernelGGL((gemm256<false, true, true>), dim3(4 * 64), dim3(512), 131072, stream,
                     P, 3072, whB, 3072, whb, (void*)(ds + 1024), 2048, 3072, 1024, 4);
  // attn: alphas -> softmax -> context into ds[:,0:1024]
  hipLaunchKernelGGL(attn_ctx, dim3(16384), dim3(256), 0, stream, P, ds);
  // G4: out1 = relu(ds @ wd1^T + b), N=2048, K=2048
  hipLaunchKernelGGL((gemm256<false, true, true>), dim3(8 * 64), dim3(512), 131072, stream,
                     ds, 2048, wd1B, 2048, wd1b, (void*)out1, 2048, 2048, 2048, 8);
  // G5: out = out1 @ wd2^T + b (fp32, N masked to 1000), K=2048
  hipLaunchKernelGGL((gemm256<false, false, false>), dim3(4 * 64), dim3(512), 131072, stream,
                     out1, 2048, wd2B, 2048, wd2b, d_out, 1000, 2048, 1000, 4);
}